// Round 12
// baseline (1283.140 us; speedup 1.0000x reference)
//
#include <hip/hip_runtime.h>
#include <hip/hip_bf16.h>
#include <hip/hip_fp16.h>
#include <cstdint>
#include <cstddef>

#define AS1 __attribute__((address_space(1)))
#define AS3 __attribute__((address_space(3)))

constexpr int HIDC   = 4096;
constexpr int INTERC = 11008;
constexpr int NTOKC  = 4096;          // B*S

using f32x16 = __attribute__((ext_vector_type(16))) float;
using f16x8  = __attribute__((ext_vector_type(8))) _Float16;

// ---------------- prologue kernels ----------------

// x f32 -> f16
__global__ void cvt_x_kernel(const float4* __restrict__ x, ushort4* __restrict__ xh, int n4) {
  int stride = gridDim.x * blockDim.x;
  for (int i = blockIdx.x * blockDim.x + threadIdx.x; i < n4; i += stride) {
    float4 v = x[i];
    ushort4 o;
    o.x = __builtin_bit_cast(unsigned short, __float2half(v.x));
    o.y = __builtin_bit_cast(unsigned short, __float2half(v.y));
    o.z = __builtin_bit_cast(unsigned short, __float2half(v.z));
    o.w = __builtin_bit_cast(unsigned short, __float2half(v.w));
    xh[i] = o;
  }
}

// Dequantize a column-chunk of W into WT[n'][K] f16 (row-major over output cols).
// GU=1: n' = (hc>>5)*64 + mat*32 + (hc&31)  (32-col gate/up interleave so each
//       wave's 2x 32-col n-blocks are the gate and up of the SAME 32 h-cols)
// GU=0: n' = n.  Block = 64 n' x 32 k tile; 256 threads = 32 k x 8 word-slots.
template <int GU>
__global__ void deq_kernel(const uint32_t* __restrict__ qw, const uint32_t* __restrict__ qz,
                           const float* __restrict__ sc, __half* __restrict__ WT,
                           int cbase, int K, int Wn8, int Nsc) {
  __shared__ __align__(16) __half tile[64][32];
  const int tid = threadIdx.x;
  const int bx = blockIdx.x;
  const int k0 = blockIdx.y * 32;
  const int k  = tid & 31, ws = tid >> 5;
  const int g  = (k0 + k) >> 7;
  int wordidx, nbase, nploc0;
  if (GU) {
    const int n0p = cbase + bx * 64;   // n' base (64-aligned)
    const int h0  = n0p >> 1;          // hc base (32-aligned)
    const int mat = ws >> 2, wsq = ws & 3;
    wordidx = (mat * INTERC + h0) / 8 + wsq;
    nbase   = mat * INTERC + h0 + wsq * 8;
    nploc0  = mat * 32 + wsq * 8;
  } else {
    const int n0 = cbase + bx * 64;
    wordidx = n0 / 8 + ws;
    nbase   = n0 + ws * 8;
    nploc0  = ws * 8;
  }
  uint32_t q  = qw[(size_t)(k0 + k) * Wn8 + wordidx];
  uint32_t zw = qz[(size_t)g * Wn8 + wordidx];
#pragma unroll
  for (int j = 0; j < 8; ++j) {
    float v = (float)((q >> (4 * j)) & 0xFu);
    float z = (float)((zw >> (4 * j)) & 0xFu);
    float s = sc[(size_t)g * Nsc + nbase + j];
    tile[nploc0 + j][k] = __float2half((v - z) * s);
  }
  __syncthreads();
  const int nl = tid >> 2, kc = (tid & 3) * 8;
  uint4 vv = *(const uint4*)&tile[nl][kc];
  *(uint4*)&WT[(size_t)(bx * 64 + nl) * K + k0 + kc] = vv;
}

// -------- pure-f16 GEMM, 256x256, 32x32x16 MFMA, counted-vmcnt pipeline --------
// 512 threads = 8 waves (2M x 4N), per-wave 128x64 out = 4m x 2n blocks of 32x32.
// LDS 128KB: 2 bufs x (A[256][64] 32KB + B[256][64] 32KB), XOR swizzle
// byte ^= (row&7)<<4 via pre-swizzled gload SOURCE (LDS dest linear).
// Per tile: 4 k-slices (K=16 each); staging for tile kt+1 spread over slices
// 0-2 (B0..B3 | A0,A2 | A1,A3); ONE barrier per tile with vmcnt(0) (all 8
// next-tile loads retired; they had >=2 slices of MFMA+LDS to land).
// Per-tile per-CU MFMA floor: 256 x 8.07 = 2066 cyc; LDS reads 96 KB.
template <int DUAL, int NT, int K>
__global__ __launch_bounds__(512, 1) void qgemm_kernel(
    const __half* __restrict__ A, const __half* __restrict__ B,
    __half* __restrict__ Hout, float* __restrict__ Fout) {
  __shared__ __align__(16) char lds[131072];
  const int tid  = threadIdx.x;
  const int lane = tid & 63;
  const int w    = tid >> 6;
  const int wr   = w >> 2, wc = w & 3;
  const int fr   = lane & 31;          // 32x32 frag row/col
  const int khf  = lane >> 5;          // k-half within K=16 frag
  const int l7   = lane & 7;

  const int nwg8 = (int)gridDim.x >> 3;
  const int g2   = ((int)blockIdx.x & 7) * nwg8 + ((int)blockIdx.x >> 3);
  const int nt   = g2 >> 4;            // 16 M-tiles, mt fastest
  const int mt   = g2 & 15;
  const int row0 = mt * 256, col0 = nt * 256;

  int a_src[4], b_src[4];
#pragma unroll
  for (int i = 0; i < 4; ++i) {
    int o = i * 8192 + tid * 16;
    int r = o >> 7;
    int b = (o & 127) ^ ((r & 7) << 4);
    a_src[i] = (row0 + r) * K + (b >> 1);
    b_src[i] = (col0 + r) * K + (b >> 1);
  }

  f32x16 acc[4][2] = {};

  auto glA = [&](int i, int kt, int buf) {
    __builtin_amdgcn_global_load_lds(
        (const AS1 uint32_t*)(A + (size_t)a_src[i] + (size_t)kt * 64),
        (AS3 uint32_t*)(lds + buf * 65536 + i * 8192 + w * 1024), 16, 0, 0);
  };
  auto glB = [&](int i, int kt, int buf) {
    __builtin_amdgcn_global_load_lds(
        (const AS1 uint32_t*)(B + (size_t)b_src[i] + (size_t)kt * 64),
        (AS3 uint32_t*)(lds + buf * 65536 + 32768 + i * 8192 + w * 1024), 16, 0, 0);
  };

  // one k-slice: read 4 A-frags + 2 B-frags (b128, conflict-clean pattern),
  // 8x 32x32x16 MFMA into distinct acc regs.
  auto slice = [&](int buf, int s) {
    const int bb = (((s << 1) | khf) ^ l7) << 4;   // swizzled phys chunk
    const char* base = lds + buf * 65536;
    f16x8 av[4], bv[2];
#pragma unroll
    for (int m = 0; m < 4; ++m)
      av[m] = *(const f16x8*)(base + (wr * 128 + m * 32 + fr) * 128 + bb);
#pragma unroll
    for (int n = 0; n < 2; ++n)
      bv[n] = *(const f16x8*)(base + 32768 + (wc * 64 + n * 32 + fr) * 128 + bb);
    __builtin_amdgcn_s_setprio(1);
#pragma unroll
    for (int m = 0; m < 4; ++m)
#pragma unroll
      for (int n = 0; n < 2; ++n)
        acc[m][n] = __builtin_amdgcn_mfma_f32_32x32x16_f16(av[m], bv[n], acc[m][n], 0, 0, 0);
    __builtin_amdgcn_s_setprio(0);
  };

  // prologue: tile 0 fully staged into buf0
  glB(0, 0, 0); glB(1, 0, 0); glB(2, 0, 0); glB(3, 0, 0);
  glA(0, 0, 0); glA(2, 0, 0); glA(1, 0, 0); glA(3, 0, 0);
  asm volatile("s_waitcnt vmcnt(0)" ::: "memory");
  asm volatile("s_barrier" ::: "memory");

#pragma unroll 1
  for (int kt = 0; kt < NT; ++kt) {
    const int cur = kt & 1, nxt = cur ^ 1;
    const bool stg = (kt + 1 < NT);
    // slice 0 + stage next-tile B
    if (stg) { glB(0, kt + 1, nxt); glB(1, kt + 1, nxt); glB(2, kt + 1, nxt); glB(3, kt + 1, nxt); }
    slice(cur, 0);
    // slice 1 + stage next-tile A (rows 0-63, 128-191)
    if (stg) { glA(0, kt + 1, nxt); glA(2, kt + 1, nxt); }
    slice(cur, 1);
    // slice 2 + stage next-tile A (rows 64-127, 192-255)
    if (stg) { glA(1, kt + 1, nxt); glA(3, kt + 1, nxt); }
    slice(cur, 2);
    // slice 3
    slice(cur, 3);
    // tile boundary: next buffer fully staged; all waves done reading cur
    asm volatile("s_waitcnt vmcnt(0)" ::: "memory");
    asm volatile("s_barrier" ::: "memory");
  }

  // ---- epilogue — 32x32 C/D map: col = lane&31, row = (r&3)+8*(r>>2)+4*(lane>>5) ----
  if (DUAL) {
    const int hcol = nt * 128 + wc * 32 + fr;
#pragma unroll
    for (int m = 0; m < 4; ++m) {
      const int rbase = row0 + wr * 128 + m * 32 + khf * 4;
#pragma unroll
      for (int r = 0; r < 16; ++r) {
        const int row = rbase + (r & 3) + ((r >> 2) << 3);
        float gv = acc[m][0][r];
        float uv = acc[m][1][r];
        float hv = gv / (1.0f + __expf(-gv)) * uv;   // silu(g)*u
        Hout[(size_t)row * INTERC + hcol] = __float2half(hv);
      }
    }
  } else {
#pragma unroll
    for (int m = 0; m < 4; ++m) {
      const int rbase = row0 + wr * 128 + m * 32 + khf * 4;
#pragma unroll
      for (int n = 0; n < 2; ++n) {
        const int cc = nt * 256 + wc * 64 + n * 32 + fr;
#pragma unroll
        for (int r = 0; r < 16; ++r) {
          const int row = rbase + (r & 3) + ((r >> 2) << 3);
          Fout[(size_t)row * HIDC + cc] = acc[m][n][r];
        }
      }
    }
  }
}

// ---------------- launch ----------------
extern "C" void kernel_launch(void* const* d_in, const int* in_sizes, int n_in,
                              void* d_out, int out_size, void* d_ws, size_t ws_size,
                              hipStream_t stream) {
  const float*    x     = (const float*)d_in[0];
  const uint32_t* qw_gu = (const uint32_t*)d_in[1];
  const uint32_t* qz_gu = (const uint32_t*)d_in[2];
  const float*    sc_gu = (const float*)d_in[3];
  const uint32_t* qw_dn = (const uint32_t*)d_in[4];
  const uint32_t* qz_dn = (const uint32_t*)d_in[5];
  const float*    sc_dn = (const float*)d_in[6];
  float* out = (float*)d_out;

  // workspace (190.9 MB peak):
  //   [0, 33.5MB)        xh (f16 x)       — dead after GEMM1
  //   [33.5, 100.7MB)    WT gu chunk (<=67.1MB)
  //   [100.7, 190.9MB)   hbuf (f16 h)
  //   WTdn (90.2MB) reuses [0, 90.2MB) after GEMM1 (stream-ordered)
  char* ws = (char*)d_ws;
  __half* xh   = (__half*)(ws);
  __half* WT   = (__half*)(ws + 33554432);
  __half* hbuf = (__half*)(ws + 100663296);
  __half* WTdn = (__half*)(ws);

  cvt_x_kernel<<<2048, 256, 0, stream>>>((const float4*)x, (ushort4*)xh, NTOKC * HIDC / 4);

  // GEMM1 in 3 col' chunks (8192, 8192, 5632 of 22016): deq -> GEMM -> next
  const int cb[3] = {0, 8192, 16384};
  const int nc[3] = {8192, 8192, 5632};
  for (int c = 0; c < 3; ++c) {
    deq_kernel<1><<<dim3(nc[c] / 64, HIDC / 32), 256, 0, stream>>>(
        qw_gu, qz_gu, sc_gu, WT, cb[c], HIDC, 2752, 22016);
    qgemm_kernel<1, 64, HIDC><<<(nc[c] / 256) * 16, 512, 0, stream>>>(
        xh, WT, hbuf + cb[c] / 2, nullptr);
  }

  // GEMM2: deq all of W_dn (into dead xh+WT region), single GEMM
  deq_kernel<0><<<dim3(HIDC / 64, INTERC / 32), 256, 0, stream>>>(
      qw_dn, qz_dn, sc_dn, WTdn, 0, INTERC, 512, HIDC);
  qgemm_kernel<0, 172, INTERC><<<(HIDC / 256) * 16, 512, 0, stream>>>(
      hbuf, WTdn, nullptr, out);
}

// Round 13
// 1154.835 us; speedup vs baseline: 1.1111x; 1.1111x over previous
//
#include <hip/hip_runtime.h>
#include <hip/hip_bf16.h>
#include <hip/hip_fp16.h>
#include <cstdint>
#include <cstddef>

#define AS1 __attribute__((address_space(1)))
#define AS3 __attribute__((address_space(3)))

constexpr int HIDC   = 4096;
constexpr int INTERC = 11008;
constexpr int NTOKC  = 4096;          // B*S

using f32x4 = __attribute__((ext_vector_type(4))) float;
using f16x8 = __attribute__((ext_vector_type(8))) _Float16;

#define BAR asm volatile("s_barrier" ::: "memory")
#define WAITL0 asm volatile("s_waitcnt lgkmcnt(0)" ::: "memory")
#define SB __builtin_amdgcn_sched_barrier(0)

// ---------------- prologue kernels ----------------

// x f32 -> f16
__global__ void cvt_x_kernel(const float4* __restrict__ x, ushort4* __restrict__ xh, int n4) {
  int stride = gridDim.x * blockDim.x;
  for (int i = blockIdx.x * blockDim.x + threadIdx.x; i < n4; i += stride) {
    float4 v = x[i];
    ushort4 o;
    o.x = __builtin_bit_cast(unsigned short, __float2half(v.x));
    o.y = __builtin_bit_cast(unsigned short, __float2half(v.y));
    o.z = __builtin_bit_cast(unsigned short, __float2half(v.z));
    o.w = __builtin_bit_cast(unsigned short, __float2half(v.w));
    xh[i] = o;
  }
}

// Dequantize a column-chunk of W into WT[n'][K] f16.
// GU=1: n' = (hc>>4)*32 + mat*16 + (hc&15)  (16-col gate/up interleave)
// GU=0: n' = n.  Block = 64 n' x 32 k tile; 256 threads = 32 k x 8 word-slots.
template <int GU>
__global__ void deq_kernel(const uint32_t* __restrict__ qw, const uint32_t* __restrict__ qz,
                           const float* __restrict__ sc, __half* __restrict__ WT,
                           int cbase, int K, int Wn8, int Nsc) {
  __shared__ __align__(16) __half tile[64][32];
  const int tid = threadIdx.x;
  const int bx = blockIdx.x;
  const int k0 = blockIdx.y * 32;
  const int k  = tid & 31, ws = tid >> 5;
  const int g  = (k0 + k) >> 7;
  int wordidx, nbase, nploc0;
  if (GU) {
    const int n0p = cbase + bx * 64;   // n' base (64-aligned)
    const int h0  = n0p >> 1;          // hc base
    const int mat = ws >> 2, wsq = ws & 3;
    wordidx = (mat * INTERC + h0) / 8 + wsq;
    nbase   = mat * INTERC + h0 + wsq * 8;
    nploc0  = ((wsq >> 1) << 5) + mat * 16 + ((wsq & 1) << 3);
  } else {
    const int n0 = cbase + bx * 64;
    wordidx = n0 / 8 + ws;
    nbase   = n0 + ws * 8;
    nploc0  = ws * 8;
  }
  uint32_t q  = qw[(size_t)(k0 + k) * Wn8 + wordidx];
  uint32_t zw = qz[(size_t)g * Wn8 + wordidx];
#pragma unroll
  for (int j = 0; j < 8; ++j) {
    float v = (float)((q >> (4 * j)) & 0xFu);
    float z = (float)((zw >> (4 * j)) & 0xFu);
    float s = sc[(size_t)g * Nsc + nbase + j];
    tile[nploc0 + j][k] = __float2half((v - z) * s);
  }
  __syncthreads();
  const int nl = tid >> 2, kc = (tid & 3) * 8;
  uint4 vv = *(const uint4*)&tile[nl][kc];
  *(uint4*)&WT[(size_t)(bx * 64 + nl) * K + k0 + kc] = vv;
}

// -------- pure-f16 GEMM, 256x256, 8-phase lockstep + counted-vmcnt --------
// 512 threads = 8 waves (2M x 4N), per-wave 128x64 out, BK=64, 16x16x32 f16.
// LDS 128KB: 2 bufs x (A[256][64] 32KB + B[256][64] 32KB), XOR swizzle
// byte ^= (row&7)<<4 via pre-swizzled gload SOURCE (LDS dest linear).
// Per tile, 4 phases (mh,kk), each phase m201-style:
//   {ds_reads + 2 gloads} -> s_barrier -> lgkmcnt(0) -> sched_barrier ->
//   setprio(1) -> 16 MFMA -> setprio(0) -> s_barrier
// Counted waits attached to closing barriers (wave-local count, fenced by the
// barrier): p1-close vmcnt(4) retires THIS tile's A-mh1 (in flight: that 2 +
// B(t+1) 4); p3-close vmcnt(2) retires B+A-mh0(t+1), leaves A-mh1(t+1) in
// flight. Never vmcnt(0) mid-loop.
template <int DUAL, int NT, int K>
__global__ __launch_bounds__(512, 1) void qgemm_kernel(
    const __half* __restrict__ A, const __half* __restrict__ B,
    __half* __restrict__ Hout, float* __restrict__ Fout) {
  __shared__ __align__(16) char lds[131072];
  const int tid  = threadIdx.x;
  const int lane = tid & 63;
  const int w    = tid >> 6;
  const int wr   = w >> 2, wc = w & 3;
  const int fr   = lane & 15, fq = lane >> 4;

  const int nwg8 = (int)gridDim.x >> 3;
  const int g2   = ((int)blockIdx.x & 7) * nwg8 + ((int)blockIdx.x >> 3);
  const int nt   = g2 >> 4;            // 16 M-tiles, mt fastest
  const int mt   = g2 & 15;
  const int row0 = mt * 256, col0 = nt * 256;

  int a_src[4], b_src[4];
#pragma unroll
  for (int i = 0; i < 4; ++i) {
    int o = i * 8192 + tid * 16;
    int r = o >> 7;
    int b = (o & 127) ^ ((r & 7) << 4);
    a_src[i] = (row0 + r) * K + (b >> 1);
    b_src[i] = (col0 + r) * K + (b >> 1);
  }

  f32x4 acc[8][4] = {};
  f16x8 av[4], bv0[4], bv1[4];

  auto glA = [&](int i, int kt, int buf) {
    __builtin_amdgcn_global_load_lds(
        (const AS1 uint32_t*)(A + (size_t)a_src[i] + (size_t)kt * 64),
        (AS3 uint32_t*)(lds + buf * 65536 + i * 8192 + w * 1024), 16, 0, 0);
  };
  auto glB = [&](int i, int kt, int buf) {
    __builtin_amdgcn_global_load_lds(
        (const AS1 uint32_t*)(B + (size_t)b_src[i] + (size_t)kt * 64),
        (AS3 uint32_t*)(lds + buf * 65536 + 32768 + i * 8192 + w * 1024), 16, 0, 0);
  };
  auto rdA = [&](int buf, int mh, int kk) {
    const int bb = (((kk << 2) | fq) ^ (fr & 7)) << 4;
    const char* base = lds + buf * 65536;
#pragma unroll
    for (int j = 0; j < 4; ++j)
      av[j] = *(const f16x8*)(base + (wr * 128 + mh * 64 + j * 16 + fr) * 128 + bb);
  };
  auto rdB = [&](int buf, int kk, f16x8* dst) {
    const int bb = (((kk << 2) | fq) ^ (fr & 7)) << 4;
    const char* base = lds + buf * 65536 + 32768;
#pragma unroll
    for (int n = 0; n < 4; ++n)
      dst[n] = *(const f16x8*)(base + (wc * 64 + n * 16 + fr) * 128 + bb);
  };
  auto mfma16 = [&](f16x8* bvp, int mh) {
    __builtin_amdgcn_s_setprio(1);
#pragma unroll
    for (int j = 0; j < 4; ++j)
#pragma unroll
      for (int n = 0; n < 4; ++n)
        acc[mh * 4 + j][n] =
            __builtin_amdgcn_mfma_f32_16x16x32_f16(av[j], bvp[n], acc[mh * 4 + j][n], 0, 0, 0);
    __builtin_amdgcn_s_setprio(0);
  };

  // prologue: tile 0, issue order B0..B3, A0, A2, A1, A3; leave A-mh1 in flight
  glB(0, 0, 0); glB(1, 0, 0); glB(2, 0, 0); glB(3, 0, 0);
  glA(0, 0, 0); glA(2, 0, 0); glA(1, 0, 0); glA(3, 0, 0);
  asm volatile("s_waitcnt vmcnt(2)" ::: "memory");
  BAR;

#pragma unroll 1
  for (int kt = 0; kt < NT; ++kt) {
    const int cur = kt & 1, nxt = cur ^ 1;
    const bool stg = (kt + 1 < NT);
    // ---- phase 0: (mh0,kk0); stage B0,B1(t+1) ----
    if (stg) { glB(0, kt + 1, nxt); glB(1, kt + 1, nxt); }
    rdB(cur, 0, bv0);
    rdA(cur, 0, 0);
    BAR; WAITL0; SB;
    mfma16(bv0, 0);
    BAR;
    // ---- phase 1: (mh0,kk1); stage B2,B3(t+1) ----
    if (stg) { glB(2, kt + 1, nxt); glB(3, kt + 1, nxt); }
    rdB(cur, 1, bv1);
    rdA(cur, 0, 1);
    BAR; WAITL0; SB;
    mfma16(bv1, 0);
    if (stg) asm volatile("s_waitcnt vmcnt(4)" ::: "memory");
    else     asm volatile("s_waitcnt vmcnt(0)" ::: "memory");
    BAR;
    // ---- phase 2: (mh1,kk0); stage A0,A2(t+1) ----
    if (stg) { glA(0, kt + 1, nxt); glA(2, kt + 1, nxt); }
    rdA(cur, 1, 0);
    BAR; WAITL0; SB;
    mfma16(bv0, 1);
    BAR;
    // ---- phase 3: (mh1,kk1); stage A1,A3(t+1) ----
    if (stg) { glA(1, kt + 1, nxt); glA(3, kt + 1, nxt); }
    rdA(cur, 1, 1);
    BAR; WAITL0; SB;
    mfma16(bv1, 1);
    if (stg) asm volatile("s_waitcnt vmcnt(2)" ::: "memory");
    BAR;
  }

  // ---- epilogue — C/D map: col = lane&15, row = (lane>>4)*4 + reg ----
  if (DUAL) {
#pragma unroll
    for (int mi = 0; mi < 8; ++mi) {
      const int rr = row0 + wr * 128 + mi * 16 + fq * 4;
#pragma unroll
      for (int pp = 0; pp < 2; ++pp) {
        const int hcol = nt * 128 + (wc * 2 + pp) * 16 + fr;
#pragma unroll
        for (int r = 0; r < 4; ++r) {
          float gv = acc[mi][2 * pp][r];
          float uv = acc[mi][2 * pp + 1][r];
          float hv = gv / (1.0f + __expf(-gv)) * uv;   // silu(g)*u
          Hout[(size_t)(rr + r) * INTERC + hcol] = __float2half(hv);
        }
      }
    }
  } else {
#pragma unroll
    for (int mi = 0; mi < 8; ++mi) {
      const int rr = row0 + wr * 128 + mi * 16 + fq * 4;
#pragma unroll
      for (int ni = 0; ni < 4; ++ni) {
        const int cc = nt * 256 + wc * 64 + ni * 16 + fr;
#pragma unroll
        for (int r = 0; r < 4; ++r)
          Fout[(size_t)(rr + r) * HIDC + cc] = acc[mi][ni][r];
      }
    }
  }
}

// ---------------- launch ----------------
extern "C" void kernel_launch(void* const* d_in, const int* in_sizes, int n_in,
                              void* d_out, int out_size, void* d_ws, size_t ws_size,
                              hipStream_t stream) {
  const float*    x     = (const float*)d_in[0];
  const uint32_t* qw_gu = (const uint32_t*)d_in[1];
  const uint32_t* qz_gu = (const uint32_t*)d_in[2];
  const float*    sc_gu = (const float*)d_in[3];
  const uint32_t* qw_dn = (const uint32_t*)d_in[4];
  const uint32_t* qz_dn = (const uint32_t*)d_in[5];
  const float*    sc_dn = (const float*)d_in[6];
  float* out = (float*)d_out;

  // workspace (190.9 MB peak):
  //   [0, 33.5MB)        xh (f16 x)       — dead after GEMM1
  //   [33.5, 100.7MB)    WT gu chunk (<=67.1MB)
  //   [100.7, 190.9MB)   hbuf (f16 h)
  //   WTdn (90.2MB) reuses [0, 90.2MB) after GEMM1 (stream-ordered)
  char* ws = (char*)d_ws;
  __half* xh   = (__half*)(ws);
  __half* WT   = (__half*)(ws + 33554432);
  __half* hbuf = (__half*)(ws + 100663296);
  __half* WTdn = (__half*)(ws);

  cvt_x_kernel<<<2048, 256, 0, stream>>>((const float4*)x, (ushort4*)xh, NTOKC * HIDC / 4);

  // GEMM1 in 3 col' chunks (8192, 8192, 5632 of 22016): deq -> GEMM -> next
  const int cb[3] = {0, 8192, 16384};
  const int nc[3] = {8192, 8192, 5632};
  for (int c = 0; c < 3; ++c) {
    deq_kernel<1><<<dim3(nc[c] / 64, HIDC / 32), 256, 0, stream>>>(
        qw_gu, qz_gu, sc_gu, WT, cb[c], HIDC, 2752, 22016);
    qgemm_kernel<1, 64, HIDC><<<(nc[c] / 256) * 16, 512, 0, stream>>>(
        xh, WT, hbuf + cb[c] / 2, nullptr);
  }

  // GEMM2: deq all of W_dn (into dead xh+WT region), single GEMM
  deq_kernel<0><<<dim3(HIDC / 64, INTERC / 32), 256, 0, stream>>>(
      qw_dn, qz_dn, sc_dn, WTdn, 0, INTERC, 512, HIDC);
  qgemm_kernel<0, 172, INTERC><<<(HIDC / 256) * 16, 512, 0, stream>>>(
      hbuf, WTdn, nullptr, out);
}

// Round 14
// 1147.341 us; speedup vs baseline: 1.1184x; 1.0065x over previous
//
#include <hip/hip_runtime.h>
#include <hip/hip_bf16.h>
#include <hip/hip_fp16.h>
#include <cstdint>
#include <cstddef>

#define AS1 __attribute__((address_space(1)))
#define AS3 __attribute__((address_space(3)))

constexpr int HIDC   = 4096;
constexpr int INTERC = 11008;
constexpr int NTOKC  = 4096;          // B*S

using f32x4 = __attribute__((ext_vector_type(4))) float;
using f16x8 = __attribute__((ext_vector_type(8))) _Float16;

// ---------------- prologue kernels ----------------

// x f32 -> f16
__global__ void cvt_x_kernel(const float4* __restrict__ x, ushort4* __restrict__ xh, int n4) {
  int stride = gridDim.x * blockDim.x;
  for (int i = blockIdx.x * blockDim.x + threadIdx.x; i < n4; i += stride) {
    float4 v = x[i];
    ushort4 o;
    o.x = __builtin_bit_cast(unsigned short, __float2half(v.x));
    o.y = __builtin_bit_cast(unsigned short, __float2half(v.y));
    o.z = __builtin_bit_cast(unsigned short, __float2half(v.z));
    o.w = __builtin_bit_cast(unsigned short, __float2half(v.w));
    xh[i] = o;
  }
}

// Dequantize a column-chunk of W into WT[n'][K] f16 (rows local to chunk).
// GU=1: n' = (hc>>4)*32 + mat*16 + (hc&15)  (16-col gate/up interleave)
// GU=0: n' = n.  Block = 64 n' x 32 k tile; 256 threads.
template <int GU>
__global__ void deq_kernel(const uint32_t* __restrict__ qw, const uint32_t* __restrict__ qz,
                           const float* __restrict__ sc, __half* __restrict__ WT,
                           int cbase, int K, int Wn8, int Nsc) {
  __shared__ __align__(16) __half tile[64][32];
  const int tid = threadIdx.x;
  const int bx = blockIdx.x;
  const int k0 = blockIdx.y * 32;
  const int k  = tid & 31, ws = tid >> 5;
  const int g  = (k0 + k) >> 7;
  int wordidx, nbase, nploc0;
  if (GU) {
    const int n0p = cbase + bx * 64;
    const int h0  = n0p >> 1;
    const int mat = ws >> 2, wsq = ws & 3;
    wordidx = (mat * INTERC + h0) / 8 + wsq;
    nbase   = mat * INTERC + h0 + wsq * 8;
    nploc0  = ((wsq >> 1) << 5) + mat * 16 + ((wsq & 1) << 3);
  } else {
    const int n0 = cbase + bx * 64;
    wordidx = n0 / 8 + ws;
    nbase   = n0 + ws * 8;
    nploc0  = ws * 8;
  }
  uint32_t q  = qw[(size_t)(k0 + k) * Wn8 + wordidx];
  uint32_t zw = qz[(size_t)g * Wn8 + wordidx];
#pragma unroll
  for (int j = 0; j < 8; ++j) {
    float v = (float)((q >> (4 * j)) & 0xFu);
    float z = (float)((zw >> (4 * j)) & 0xFu);
    float s = sc[(size_t)g * Nsc + nbase + j];
    tile[nploc0 + j][k] = __float2half((v - z) * s);
  }
  __syncthreads();
  const int nl = tid >> 2, kc = (tid & 3) * 8;
  uint4 vv = *(const uint4*)&tile[nl][kc];
  *(uint4*)&WT[(size_t)(bx * 64 + nl) * K + k0 + kc] = vv;
}

// -------- fused GEMM1 sub-chunk (R11 pipeline) + deq-slice of NEXT sub --------
// 512 threads = 8 waves (2M x 4N), per-wave 128x64 out, BK=64, 16x16x32 f16.
// LDS 128KB: 2 bufs x (A 32KB + B 32KB), XOR swizzle byte^=(row&7)<<4 via
// pre-swizzled gload SOURCE. Counted vmcnt(4)/vmcnt(2); never vmcnt(0) mid-loop.
// Phase A (bid < ndq): dequant 16 cols x K=4096 of the NEXT sub into Bnext
// (ring slot not read by this dispatch) using LDS before GEMM staging claims it.
__global__ __launch_bounds__(512, 1) void g1f_kernel(
    const __half* __restrict__ A, const __half* __restrict__ Bcur,
    __half* __restrict__ Hout,
    const uint32_t* __restrict__ qw, const uint32_t* __restrict__ qz,
    const float* __restrict__ sc, __half* __restrict__ Bnext,
    int cb_next, int ndq, int ng) {
  __shared__ __align__(16) char lds[131072];
  const int tid  = threadIdx.x;
  const int bid  = blockIdx.x;

  // ---- phase A: deq-slice of next sub (no cross-block deps; consumed next dispatch) ----
  if (bid < ndq) {
    __half* tile = (__half*)lds;               // [16][256]
    const int pg  = cb_next + bid * 16;        // global n' base (16-aligned)
    const int mat = (pg >> 4) & 1;
    const int hcb = (pg >> 5) << 4;            // hc base
    const int cw  = tid >> 8;                  // 0..1 word within slice
    const int k   = tid & 255;
    const int wordidx = mat * (INTERC / 8) + (hcb >> 3) + cw;
#pragma unroll 1
    for (int it = 0; it < HIDC / 256; ++it) {
      const int kk = it * 256 + k;
      const int g  = kk >> 7;
      uint32_t q  = qw[(size_t)kk * (2 * INTERC / 8) + wordidx];
      uint32_t zw = qz[(size_t)g * (2 * INTERC / 8) + wordidx];
      const float* sp = sc + (size_t)g * (2 * INTERC) + mat * INTERC + hcb + cw * 8;
      float4 s0 = *(const float4*)sp;
      float4 s1 = *(const float4*)(sp + 4);
      float ss[8] = {s0.x, s0.y, s0.z, s0.w, s1.x, s1.y, s1.z, s1.w};
#pragma unroll
      for (int j = 0; j < 8; ++j) {
        float v = (float)((q >> (4 * j)) & 0xFu);
        float z = (float)((zw >> (4 * j)) & 0xFu);
        tile[(cw * 8 + j) * 256 + k] = __float2half((v - z) * ss[j]);
      }
      __syncthreads();
      const int nl = tid >> 5, kc = (tid & 31) * 8;
      uint4 vv = *(const uint4*)&tile[nl * 256 + kc];
      *(uint4*)&Bnext[(size_t)(bid * 16 + nl) * HIDC + it * 256 + kc] = vv;
      __syncthreads();
    }
  }
  __syncthreads();

  // ---- phase B: R11 GEMM (DUAL), NT = HIDC/64 = 64 K-tiles ----
  constexpr int NT = HIDC / 64;
  constexpr int K  = HIDC;
  const int lane = tid & 63;
  const int w    = tid >> 6;
  const int wr   = w >> 2, wc = w & 3;
  const int fr   = lane & 15, fq = lane >> 4;

  const int nwg8 = ng >> 3;
  const int g2   = (bid & 7) * nwg8 + (bid >> 3);
  const int nt   = g2 >> 4;            // 16 M-tiles, mt fastest
  const int mt   = g2 & 15;
  const int row0 = mt * 256, col0 = nt * 256;

  int a_src[4], b_src[4];
#pragma unroll
  for (int i = 0; i < 4; ++i) {
    int o = i * 8192 + tid * 16;
    int r = o >> 7;
    int b = (o & 127) ^ ((r & 7) << 4);
    a_src[i] = (row0 + r) * K + (b >> 1);
    b_src[i] = (col0 + r) * K + (b >> 1);
  }

  f32x4 acc[8][4] = {};
  f16x8 av[4], bv0[4], bv1[4];

  auto glA = [&](int i, int kt, int buf) {
    __builtin_amdgcn_global_load_lds(
        (const AS1 uint32_t*)(A + (size_t)a_src[i] + (size_t)kt * 64),
        (AS3 uint32_t*)(lds + buf * 65536 + i * 8192 + w * 1024), 16, 0, 0);
  };
  auto glB = [&](int i, int kt, int buf) {
    __builtin_amdgcn_global_load_lds(
        (const AS1 uint32_t*)(Bcur + (size_t)b_src[i] + (size_t)kt * 64),
        (AS3 uint32_t*)(lds + buf * 65536 + 32768 + i * 8192 + w * 1024), 16, 0, 0);
  };
  auto rdA = [&](int buf, int mh, int kk) {
    const int bb = (((kk << 2) | fq) ^ (fr & 7)) << 4;
    const char* base = lds + buf * 65536;
#pragma unroll
    for (int j = 0; j < 4; ++j)
      av[j] = *(const f16x8*)(base + (wr * 128 + mh * 64 + j * 16 + fr) * 128 + bb);
  };
  auto rdB = [&](int buf, int kk, f16x8* dst) {
    const int bb = (((kk << 2) | fq) ^ (fr & 7)) << 4;
    const char* base = lds + buf * 65536 + 32768;
#pragma unroll
    for (int n = 0; n < 4; ++n)
      dst[n] = *(const f16x8*)(base + (wc * 64 + n * 16 + fr) * 128 + bb);
  };
  auto mfma16 = [&](f16x8* bvp, int mh) {
    __builtin_amdgcn_s_setprio(1);
#pragma unroll
    for (int j = 0; j < 4; ++j)
#pragma unroll
      for (int n = 0; n < 4; ++n)
        acc[mh * 4 + j][n] =
            __builtin_amdgcn_mfma_f32_16x16x32_f16(av[j], bvp[n], acc[mh * 4 + j][n], 0, 0, 0);
    __builtin_amdgcn_s_setprio(0);
  };

  glB(0, 0, 0); glB(1, 0, 0); glB(2, 0, 0); glB(3, 0, 0);
  glA(0, 0, 0); glA(2, 0, 0); glA(1, 0, 0); glA(3, 0, 0);
  asm volatile("s_waitcnt vmcnt(2)" ::: "memory");
  asm volatile("s_barrier" ::: "memory");

#pragma unroll 1
  for (int kt = 0; kt < NT; ++kt) {
    const int cur = kt & 1, nxt = cur ^ 1;
    const bool stg = (kt + 1 < NT);
    if (stg) { glB(0, kt + 1, nxt); glB(1, kt + 1, nxt); }
    rdB(cur, 0, bv0);
    rdA(cur, 0, 0);
    mfma16(bv0, 0);
    if (stg) { glB(2, kt + 1, nxt); glB(3, kt + 1, nxt); }
    rdB(cur, 1, bv1);
    rdA(cur, 0, 1);
    mfma16(bv1, 0);
    if (stg) asm volatile("s_waitcnt vmcnt(4)" ::: "memory");
    else     asm volatile("s_waitcnt vmcnt(0)" ::: "memory");
    asm volatile("s_barrier" ::: "memory");
    if (stg) { glA(0, kt + 1, nxt); glA(2, kt + 1, nxt); }
    rdA(cur, 1, 0);
    mfma16(bv0, 1);
    if (stg) { glA(1, kt + 1, nxt); glA(3, kt + 1, nxt); }
    rdA(cur, 1, 1);
    mfma16(bv1, 1);
    if (stg) asm volatile("s_waitcnt vmcnt(2)" ::: "memory");
    asm volatile("s_barrier" ::: "memory");
  }

  // epilogue — C/D map: col = lane&15, row = (lane>>4)*4 + reg
#pragma unroll
  for (int mi = 0; mi < 8; ++mi) {
    const int rr = row0 + wr * 128 + mi * 16 + fq * 4;
#pragma unroll
    for (int pp = 0; pp < 2; ++pp) {
      const int hcol = nt * 128 + (wc * 2 + pp) * 16 + fr;
#pragma unroll
      for (int r = 0; r < 4; ++r) {
        float gv = acc[mi][2 * pp][r];
        float uv = acc[mi][2 * pp + 1][r];
        float hv = gv / (1.0f + __expf(-gv)) * uv;   // silu(g)*u
        Hout[(size_t)(rr + r) * INTERC + hcol] = __float2half(hv);
      }
    }
  }
}

// -------- pure-f16 GEMM2 (R11 verbatim, DUAL=0) --------
template <int NT, int K>
__global__ __launch_bounds__(512, 1) void qgemm_kernel(
    const __half* __restrict__ A, const __half* __restrict__ B,
    float* __restrict__ Fout) {
  __shared__ __align__(16) char lds[131072];
  const int tid  = threadIdx.x;
  const int lane = tid & 63;
  const int w    = tid >> 6;
  const int wr   = w >> 2, wc = w & 3;
  const int fr   = lane & 15, fq = lane >> 4;

  const int nwg8 = (int)gridDim.x >> 3;
  const int g2   = ((int)blockIdx.x & 7) * nwg8 + ((int)blockIdx.x >> 3);
  const int nt   = g2 >> 4;
  const int mt   = g2 & 15;
  const int row0 = mt * 256, col0 = nt * 256;

  int a_src[4], b_src[4];
#pragma unroll
  for (int i = 0; i < 4; ++i) {
    int o = i * 8192 + tid * 16;
    int r = o >> 7;
    int b = (o & 127) ^ ((r & 7) << 4);
    a_src[i] = (row0 + r) * K + (b >> 1);
    b_src[i] = (col0 + r) * K + (b >> 1);
  }

  f32x4 acc[8][4] = {};
  f16x8 av[4], bv0[4], bv1[4];

  auto glA = [&](int i, int kt, int buf) {
    __builtin_amdgcn_global_load_lds(
        (const AS1 uint32_t*)(A + (size_t)a_src[i] + (size_t)kt * 64),
        (AS3 uint32_t*)(lds + buf * 65536 + i * 8192 + w * 1024), 16, 0, 0);
  };
  auto glB = [&](int i, int kt, int buf) {
    __builtin_amdgcn_global_load_lds(
        (const AS1 uint32_t*)(B + (size_t)b_src[i] + (size_t)kt * 64),
        (AS3 uint32_t*)(lds + buf * 65536 + 32768 + i * 8192 + w * 1024), 16, 0, 0);
  };
  auto rdA = [&](int buf, int mh, int kk) {
    const int bb = (((kk << 2) | fq) ^ (fr & 7)) << 4;
    const char* base = lds + buf * 65536;
#pragma unroll
    for (int j = 0; j < 4; ++j)
      av[j] = *(const f16x8*)(base + (wr * 128 + mh * 64 + j * 16 + fr) * 128 + bb);
  };
  auto rdB = [&](int buf, int kk, f16x8* dst) {
    const int bb = (((kk << 2) | fq) ^ (fr & 7)) << 4;
    const char* base = lds + buf * 65536 + 32768;
#pragma unroll
    for (int n = 0; n < 4; ++n)
      dst[n] = *(const f16x8*)(base + (wc * 64 + n * 16 + fr) * 128 + bb);
  };
  auto mfma16 = [&](f16x8* bvp, int mh) {
    __builtin_amdgcn_s_setprio(1);
#pragma unroll
    for (int j = 0; j < 4; ++j)
#pragma unroll
      for (int n = 0; n < 4; ++n)
        acc[mh * 4 + j][n] =
            __builtin_amdgcn_mfma_f32_16x16x32_f16(av[j], bvp[n], acc[mh * 4 + j][n], 0, 0, 0);
    __builtin_amdgcn_s_setprio(0);
  };

  glB(0, 0, 0); glB(1, 0, 0); glB(2, 0, 0); glB(3, 0, 0);
  glA(0, 0, 0); glA(2, 0, 0); glA(1, 0, 0); glA(3, 0, 0);
  asm volatile("s_waitcnt vmcnt(2)" ::: "memory");
  asm volatile("s_barrier" ::: "memory");

#pragma unroll 1
  for (int kt = 0; kt < NT; ++kt) {
    const int cur = kt & 1, nxt = cur ^ 1;
    const bool stg = (kt + 1 < NT);
    if (stg) { glB(0, kt + 1, nxt); glB(1, kt + 1, nxt); }
    rdB(cur, 0, bv0);
    rdA(cur, 0, 0);
    mfma16(bv0, 0);
    if (stg) { glB(2, kt + 1, nxt); glB(3, kt + 1, nxt); }
    rdB(cur, 1, bv1);
    rdA(cur, 0, 1);
    mfma16(bv1, 0);
    if (stg) asm volatile("s_waitcnt vmcnt(4)" ::: "memory");
    else     asm volatile("s_waitcnt vmcnt(0)" ::: "memory");
    asm volatile("s_barrier" ::: "memory");
    if (stg) { glA(0, kt + 1, nxt); glA(2, kt + 1, nxt); }
    rdA(cur, 1, 0);
    mfma16(bv0, 1);
    if (stg) { glA(1, kt + 1, nxt); glA(3, kt + 1, nxt); }
    rdA(cur, 1, 1);
    mfma16(bv1, 1);
    if (stg) asm volatile("s_waitcnt vmcnt(2)" ::: "memory");
    asm volatile("s_barrier" ::: "memory");
  }

#pragma unroll
  for (int mi = 0; mi < 8; ++mi) {
    const int rr = row0 + wr * 128 + mi * 16 + fq * 4;
#pragma unroll
    for (int ni = 0; ni < 4; ++ni) {
      const int cc = nt * 256 + wc * 64 + ni * 16 + fr;
#pragma unroll
      for (int r = 0; r < 4; ++r)
        Fout[(size_t)(rr + r) * HIDC + cc] = acc[mi][ni][r];
    }
  }
}

// ---------------- launch ----------------
extern "C" void kernel_launch(void* const* d_in, const int* in_sizes, int n_in,
                              void* d_out, int out_size, void* d_ws, size_t ws_size,
                              hipStream_t stream) {
  const float*    x     = (const float*)d_in[0];
  const uint32_t* qw_gu = (const uint32_t*)d_in[1];
  const uint32_t* qz_gu = (const uint32_t*)d_in[2];
  const float*    sc_gu = (const float*)d_in[3];
  const uint32_t* qw_dn = (const uint32_t*)d_in[4];
  const uint32_t* qz_dn = (const uint32_t*)d_in[5];
  const float*    sc_dn = (const float*)d_in[6];
  float* out = (float*)d_out;

  // workspace (190.9 MB peak):
  //   [0, 33.5MB)        xh             — dead after GEMM1
  //   [33.5, 67.1MB)     WT ring slot 0 (4096 cols)
  //   [67.1, 100.7MB)    WT ring slot 1
  //   [100.7, 190.9MB)   hbuf
  //   WTdn (90.2MB) reuses [0, 90.2MB) after GEMM1 (stream-ordered)
  char* ws = (char*)d_ws;
  __half* xh    = (__half*)(ws);
  __half* WTs[2] = {(__half*)(ws + 33554432), (__half*)(ws + 67108864)};
  __half* hbuf  = (__half*)(ws + 100663296);
  __half* WTdn  = (__half*)(ws);

  cvt_x_kernel<<<2048, 256, 0, stream>>>((const float4*)x, (ushort4*)xh, NTOKC * HIDC / 4);
  // deq sub0 (4096 cols) into slot 0
  deq_kernel<1><<<dim3(64, 128), 256, 0, stream>>>(
      qw_gu, qz_gu, sc_gu, WTs[0], 0, HIDC, 2 * INTERC / 8, 2 * INTERC);

  // GEMM1: 6 subs {4096 x5, 1536}; each dispatch fuses deq-slice of next sub
  const int cbs[7] = {0, 4096, 8192, 12288, 16384, 20480, 22016};
  for (int k = 0; k < 6; ++k) {
    const int nc  = cbs[k + 1] - cbs[k];
    const int ng  = (nc / 256) * 16;                       // 256 or 96
    const int ncn = (k < 5) ? (cbs[k + 2] - cbs[k + 1]) : 0;
    const int ndq = ncn / 16;                              // 256, ..., 96, 0
    g1f_kernel<<<ng, 512, 0, stream>>>(
        xh, WTs[k & 1], hbuf + cbs[k] / 2,
        qw_gu, qz_gu, sc_gu, WTs[(k + 1) & 1], cbs[k + 1], ndq, ng);
  }

  // GEMM2: deq all of W_dn (into dead xh+ring region), single GEMM
  deq_kernel<0><<<dim3(HIDC / 64, INTERC / 32), 256, 0, stream>>>(
      qw_dn, qz_dn, sc_dn, WTdn, 0, INTERC, HIDC / 8, HIDC);
  qgemm_kernel<172, INTERC><<<(HIDC / 256) * 16, 512, 0, stream>>>(hbuf, WTdn, out);
}

// Round 15
// 1091.898 us; speedup vs baseline: 1.1751x; 1.0508x over previous
//
#include <hip/hip_runtime.h>
#include <hip/hip_bf16.h>
#include <hip/hip_fp16.h>
#include <cstdint>
#include <cstddef>

#define AS1 __attribute__((address_space(1)))
#define AS3 __attribute__((address_space(3)))

constexpr int HIDC   = 4096;
constexpr int INTERC = 11008;
constexpr int NTOKC  = 4096;          // B*S

using f32x4 = __attribute__((ext_vector_type(4))) float;
using f16x8 = __attribute__((ext_vector_type(8))) _Float16;

// ---------------- prologue kernels ----------------

// x f32 -> f16
__global__ void cvt_x_kernel(const float4* __restrict__ x, ushort4* __restrict__ xh, int n4) {
  int stride = gridDim.x * blockDim.x;
  for (int i = blockIdx.x * blockDim.x + threadIdx.x; i < n4; i += stride) {
    float4 v = x[i];
    ushort4 o;
    o.x = __builtin_bit_cast(unsigned short, __float2half(v.x));
    o.y = __builtin_bit_cast(unsigned short, __float2half(v.y));
    o.z = __builtin_bit_cast(unsigned short, __float2half(v.z));
    o.w = __builtin_bit_cast(unsigned short, __float2half(v.w));
    xh[i] = o;
  }
}

// Dequantize a column-chunk of W into WT[n'][K] f16 (rows local to chunk).
// GU=1: n' = (hc>>4)*32 + mat*16 + (hc&15)  (16-col gate/up interleave)
// GU=0: n' = n.  Block = 64 n' x 32 k tile; 256 threads = 32 k x 8 word-slots.
// R15: scale loads vectorized (2x float4 instead of 8 scalar) — nbase is
// 8-float (32B) aligned by construction.
template <int GU>
__global__ void deq_kernel(const uint32_t* __restrict__ qw, const uint32_t* __restrict__ qz,
                           const float* __restrict__ sc, __half* __restrict__ WT,
                           int cbase, int K, int Wn8, int Nsc) {
  __shared__ __align__(16) __half tile[64][32];
  const int tid = threadIdx.x;
  const int bx = blockIdx.x;
  const int k0 = blockIdx.y * 32;
  const int k  = tid & 31, ws = tid >> 5;
  const int g  = (k0 + k) >> 7;
  int wordidx, nbase, nploc0;
  if (GU) {
    const int n0p = cbase + bx * 64;
    const int h0  = n0p >> 1;
    const int mat = ws >> 2, wsq = ws & 3;
    wordidx = (mat * INTERC + h0) / 8 + wsq;
    nbase   = mat * INTERC + h0 + wsq * 8;
    nploc0  = ((wsq >> 1) << 5) + mat * 16 + ((wsq & 1) << 3);
  } else {
    const int n0 = cbase + bx * 64;
    wordidx = n0 / 8 + ws;
    nbase   = n0 + ws * 8;
    nploc0  = ws * 8;
  }
  uint32_t q  = qw[(size_t)(k0 + k) * Wn8 + wordidx];
  uint32_t zw = qz[(size_t)g * Wn8 + wordidx];
  const float* sp = sc + (size_t)g * Nsc + nbase;
  float4 s0 = *(const float4*)sp;
  float4 s1 = *(const float4*)(sp + 4);
  const float ss[8] = {s0.x, s0.y, s0.z, s0.w, s1.x, s1.y, s1.z, s1.w};
#pragma unroll
  for (int j = 0; j < 8; ++j) {
    float v = (float)((q >> (4 * j)) & 0xFu);
    float z = (float)((zw >> (4 * j)) & 0xFu);
    tile[nploc0 + j][k] = __float2half((v - z) * ss[j]);
  }
  __syncthreads();
  const int nl = tid >> 2, kc = (tid & 3) * 8;
  uint4 vv = *(const uint4*)&tile[nl][kc];
  *(uint4*)&WT[(size_t)(bx * 64 + nl) * K + k0 + kc] = vv;
}

// -------- pure-f16 GEMM, 256x256, counted-vmcnt depth-1.5 pipeline --------
// 512 threads = 8 waves (2M x 4N), per-wave 128x64 out, BK=64, 16x16x32 f16 MFMA.
// LDS 128KB: 2 bufs x (A[256][64] 32KB + B[256][64] 32KB), XOR swizzle
// byte ^= (row&7)<<4 via pre-swizzled gload SOURCE (LDS dest linear).
// Grid: 1D, bijective XCD chunking (grid%8==0), mt fastest within a chunk.
// Waits: end-ph2 vmcnt(4) (retires THIS tile's A-h1), end-ph4 vmcnt(2)
// (retires next tile's B + A-h0; A-h1 stays in flight). Never vmcnt(0) mid-loop.
template <int DUAL, int NT, int K>
__global__ __launch_bounds__(512, 1) void qgemm_kernel(
    const __half* __restrict__ A, const __half* __restrict__ B,
    __half* __restrict__ Hout, float* __restrict__ Fout) {
  __shared__ __align__(16) char lds[131072];
  const int tid  = threadIdx.x;
  const int lane = tid & 63;
  const int w    = tid >> 6;
  const int wr   = w >> 2, wc = w & 3;
  const int fr   = lane & 15, fq = lane >> 4;

  const int nwg8 = (int)gridDim.x >> 3;
  const int g2   = ((int)blockIdx.x & 7) * nwg8 + ((int)blockIdx.x >> 3);
  const int nt   = g2 >> 4;            // 16 M-tiles, mt fastest
  const int mt   = g2 & 15;
  const int row0 = mt * 256, col0 = nt * 256;

  int a_src[4], b_src[4];
#pragma unroll
  for (int i = 0; i < 4; ++i) {
    int o = i * 8192 + tid * 16;
    int r = o >> 7;
    int b = (o & 127) ^ ((r & 7) << 4);
    a_src[i] = (row0 + r) * K + (b >> 1);
    b_src[i] = (col0 + r) * K + (b >> 1);
  }

  f32x4 acc[8][4] = {};
  f16x8 av[4], bv0[4], bv1[4];

  auto glA = [&](int i, int kt, int buf) {
    __builtin_amdgcn_global_load_lds(
        (const AS1 uint32_t*)(A + (size_t)a_src[i] + (size_t)kt * 64),
        (AS3 uint32_t*)(lds + buf * 65536 + i * 8192 + w * 1024), 16, 0, 0);
  };
  auto glB = [&](int i, int kt, int buf) {
    __builtin_amdgcn_global_load_lds(
        (const AS1 uint32_t*)(B + (size_t)b_src[i] + (size_t)kt * 64),
        (AS3 uint32_t*)(lds + buf * 65536 + 32768 + i * 8192 + w * 1024), 16, 0, 0);
  };
  auto rdA = [&](int buf, int mh, int kk) {
    const int bb = (((kk << 2) | fq) ^ (fr & 7)) << 4;
    const char* base = lds + buf * 65536;
#pragma unroll
    for (int j = 0; j < 4; ++j)
      av[j] = *(const f16x8*)(base + (wr * 128 + mh * 64 + j * 16 + fr) * 128 + bb);
  };
  auto rdB = [&](int buf, int kk, f16x8* dst) {
    const int bb = (((kk << 2) | fq) ^ (fr & 7)) << 4;
    const char* base = lds + buf * 65536 + 32768;
#pragma unroll
    for (int n = 0; n < 4; ++n)
      dst[n] = *(const f16x8*)(base + (wc * 64 + n * 16 + fr) * 128 + bb);
  };
  auto mfma16 = [&](f16x8* bvp, int mh) {
    __builtin_amdgcn_s_setprio(1);
#pragma unroll
    for (int j = 0; j < 4; ++j)
#pragma unroll
      for (int n = 0; n < 4; ++n)
        acc[mh * 4 + j][n] =
            __builtin_amdgcn_mfma_f32_16x16x32_f16(av[j], bvp[n], acc[mh * 4 + j][n], 0, 0, 0);
    __builtin_amdgcn_s_setprio(0);
  };

  // prologue: tile 0, issue order B0..B3, A0, A2, A1, A3; leave A-h1 in flight
  glB(0, 0, 0); glB(1, 0, 0); glB(2, 0, 0); glB(3, 0, 0);
  glA(0, 0, 0); glA(2, 0, 0); glA(1, 0, 0); glA(3, 0, 0);
  asm volatile("s_waitcnt vmcnt(2)" ::: "memory");
  asm volatile("s_barrier" ::: "memory");

#pragma unroll 1
  for (int kt = 0; kt < NT; ++kt) {
    const int cur = kt & 1, nxt = cur ^ 1;
    const bool stg = (kt + 1 < NT);
    // ph1: (mh0, kk0)
    if (stg) { glB(0, kt + 1, nxt); glB(1, kt + 1, nxt); }
    rdB(cur, 0, bv0);
    rdA(cur, 0, 0);
    mfma16(bv0, 0);
    // ph2: (mh0, kk1)
    if (stg) { glB(2, kt + 1, nxt); glB(3, kt + 1, nxt); }
    rdB(cur, 1, bv1);
    rdA(cur, 0, 1);
    mfma16(bv1, 0);
    if (stg) asm volatile("s_waitcnt vmcnt(4)" ::: "memory");
    else     asm volatile("s_waitcnt vmcnt(0)" ::: "memory");
    asm volatile("s_barrier" ::: "memory");
    // ph3: (mh1, kk0)
    if (stg) { glA(0, kt + 1, nxt); glA(2, kt + 1, nxt); }
    rdA(cur, 1, 0);
    mfma16(bv0, 1);
    // ph4: (mh1, kk1)
    if (stg) { glA(1, kt + 1, nxt); glA(3, kt + 1, nxt); }
    rdA(cur, 1, 1);
    mfma16(bv1, 1);
    if (stg) asm volatile("s_waitcnt vmcnt(2)" ::: "memory");
    asm volatile("s_barrier" ::: "memory");
  }

  // ---- epilogue — C/D map: col = lane&15, row = (lane>>4)*4 + reg ----
  if (DUAL) {
#pragma unroll
    for (int mi = 0; mi < 8; ++mi) {
      const int rr = row0 + wr * 128 + mi * 16 + fq * 4;
#pragma unroll
      for (int pp = 0; pp < 2; ++pp) {
        const int hcol = nt * 128 + (wc * 2 + pp) * 16 + fr;
#pragma unroll
        for (int r = 0; r < 4; ++r) {
          float gv = acc[mi][2 * pp][r];
          float uv = acc[mi][2 * pp + 1][r];
          float hv = gv / (1.0f + __expf(-gv)) * uv;   // silu(g)*u
          Hout[(size_t)(rr + r) * INTERC + hcol] = __float2half(hv);
        }
      }
    }
  } else {
#pragma unroll
    for (int mi = 0; mi < 8; ++mi) {
      const int rr = row0 + wr * 128 + mi * 16 + fq * 4;
#pragma unroll
      for (int ni = 0; ni < 4; ++ni) {
        const int cc = nt * 256 + wc * 64 + ni * 16 + fr;
#pragma unroll
        for (int r = 0; r < 4; ++r)
          Fout[(size_t)(rr + r) * HIDC + cc] = acc[mi][ni][r];
      }
    }
  }
}

// ---------------- launch ----------------
extern "C" void kernel_launch(void* const* d_in, const int* in_sizes, int n_in,
                              void* d_out, int out_size, void* d_ws, size_t ws_size,
                              hipStream_t stream) {
  const float*    x     = (const float*)d_in[0];
  const uint32_t* qw_gu = (const uint32_t*)d_in[1];
  const uint32_t* qz_gu = (const uint32_t*)d_in[2];
  const float*    sc_gu = (const float*)d_in[3];
  const uint32_t* qw_dn = (const uint32_t*)d_in[4];
  const uint32_t* qz_dn = (const uint32_t*)d_in[5];
  const float*    sc_dn = (const float*)d_in[6];
  float* out = (float*)d_out;

  // workspace (190.9 MB peak):
  //   [0, 33.5MB)        xh (f16 x)       — dead after GEMM1
  //   [33.5, 100.7MB)    WT gu chunk (<=67.1MB)
  //   [100.7, 190.9MB)   hbuf (f16 h)
  //   WTdn (90.2MB) reuses [0, 90.2MB) after GEMM1 (stream-ordered)
  char* ws = (char*)d_ws;
  __half* xh   = (__half*)(ws);
  __half* WT   = (__half*)(ws + 33554432);
  __half* hbuf = (__half*)(ws + 100663296);
  __half* WTdn = (__half*)(ws);

  cvt_x_kernel<<<2048, 256, 0, stream>>>((const float4*)x, (ushort4*)xh, NTOKC * HIDC / 4);

  // GEMM1 in 3 col' chunks (8192, 8192, 5632 of 22016): deq -> GEMM -> next
  const int cb[3] = {0, 8192, 16384};
  const int nc[3] = {8192, 8192, 5632};
  for (int c = 0; c < 3; ++c) {
    deq_kernel<1><<<dim3(nc[c] / 64, HIDC / 32), 256, 0, stream>>>(
        qw_gu, qz_gu, sc_gu, WT, cb[c], HIDC, 2 * INTERC / 8, 2 * INTERC);
    qgemm_kernel<1, 64, HIDC><<<(nc[c] / 256) * 16, 512, 0, stream>>>(
        xh, WT, hbuf + cb[c] / 2, nullptr);
  }

  // GEMM2: deq all of W_dn (into dead xh+WT region), single GEMM
  deq_kernel<0><<<dim3(HIDC / 64, INTERC / 32), 256, 0, stream>>>(
      qw_dn, qz_dn, sc_dn, WTdn, 0, INTERC, HIDC / 8, HIDC);
  qgemm_kernel<0, 172, INTERC><<<(HIDC / 256) * 16, 512, 0, stream>>>(
      hbuf, WTdn, nullptr, out);
}